// Round 2
// baseline (428.138 us; speedup 1.0000x reference)
//
#include <hip/hip_runtime.h>

#define NUM_CARDS 50000
#define NM1 49999
#define BATCH 1024
#define NTILES 3125            // 3125*16 = 50000 = NM1 + 1 pad column
#define GRIDY 125              // 125 * 25 = 3125 tiles, 25 tiles per y-block
#define TPB   25
#define LOGEPS -16.118095651f  // ln(1e-7)
#define KLEPS 1e-7f

typedef __attribute__((ext_vector_type(8))) short short8;  // 8 bf16 in 4 VGPRs
typedef __attribute__((ext_vector_type(4))) float f32x4;

// ws layout:
//   A bf16   : [0,       131072)   1024*64*2
//   B bf16   : [131072,  6531072)  50000*64*2 (row j = normalized card j+1; row 49999 = 0)
//   sumexp   : [6531072, 6535168)  1024*4   (holds true_sumexp + 1 due to pad column)
//   acc      : [6535168, 6535172)
#define A_OFF   0
#define B_OFF   131072
#define SUM_OFF 6531072
#define ACC_OFF 6535168

__device__ inline unsigned short f2bf(float x) {
    unsigned int u = __float_as_uint(x);
    return (unsigned short)((u + 0x7FFFu + ((u >> 16) & 1u)) >> 16);  // RNE
}

// ---- fused prep: blocks [0,12500) normalize B; blocks [12500,12628) run the MLP ----
__global__ __launch_bounds__(256) void prep_kernel(
    const int* __restrict__ idx, const float* __restrict__ ce,
    const float* __restrict__ W1, const float* __restrict__ b1,
    const float* __restrict__ W2, const float* __restrict__ b2,
    unsigned short* __restrict__ Abf, unsigned short* __restrict__ Bbf,
    float* __restrict__ sumexp, float* __restrict__ acc)
{
    const int bid = blockIdx.x;
    const int t   = threadIdx.x;
    const int lane = t & 63;
    const int wv   = t >> 6;

    if (bid < 12500) {
        // normalize card_embeddings[1:] -> bf16 B (row j = card j+1), row 49999 = 0
        const int j = bid * 4 + wv;
        float v = (j < NM1) ? ce[(size_t)(j + 1) * 64 + lane] : 0.f;
        float ss = v * v;
        #pragma unroll
        for (int m = 1; m <= 32; m <<= 1) ss += __shfl_xor(ss, m, 64);
        float inv = rsqrtf(fmaxf(ss, 1e-12f));
        Bbf[(size_t)j * 64 + lane] = f2bf((j < NM1) ? v * inv : 0.f);
        return;
    }

    // ---- MLP path: 8 batch rows per block ----
    if (bid == 12500) {  // also zero sumexp + acc (safe: consumed by later kernels)
        sumexp[t] = 0.f; sumexp[256 + t] = 0.f; sumexp[512 + t] = 0.f; sumexp[768 + t] = 0.f;
        if (t == 0) acc[0] = 0.f;
    }
    __shared__ float emb_s[8][64];
    __shared__ float hs[8][256];
    __shared__ int idx_s[8];
    const int i0 = (bid - 12500) * 8;
    if (t < 8) idx_s[t] = idx[i0 + t];
    __syncthreads();
    for (int e = t; e < 8 * 64; e += 256) {
        int g = e >> 6, k = e & 63;
        emb_s[g][k] = ce[idx_s[g] * 64 + k];
    }
    __syncthreads();
    {   // hidden layer: thread j computes h[g][j] for all 8 g
        const int j = t;
        float a8[8];
        float bj = b1[j];
        #pragma unroll
        for (int g = 0; g < 8; ++g) a8[g] = bj;
        for (int k = 0; k < 64; ++k) {
            float w = W1[k * 256 + j];
            #pragma unroll
            for (int g = 0; g < 8; ++g) a8[g] = fmaf(emb_s[g][k], w, a8[g]);
        }
        #pragma unroll
        for (int g = 0; g < 8; ++g) hs[g][j] = fmaxf(a8[g], 0.f);
    }
    __syncthreads();
    {   // output layer: wave wv handles rows wv and wv+4, lane = dim d
        const int d = lane;
        float o0 = b2[d], o1 = b2[d];
        for (int j = 0; j < 256; ++j) {
            float w2 = W2[j * 64 + d];
            o0 = fmaf(hs[wv][j],     w2, o0);
            o1 = fmaf(hs[wv + 4][j], w2, o1);
        }
        float s0 = o0 * o0, s1 = o1 * o1;
        #pragma unroll
        for (int m = 1; m <= 32; m <<= 1) {
            s0 += __shfl_xor(s0, m, 64);
            s1 += __shfl_xor(s1, m, 64);
        }
        o0 *= rsqrtf(fmaxf(s0, 1e-12f));
        o1 *= rsqrtf(fmaxf(s1, 1e-12f));
        Abf[(i0 + wv) * 64 + d]     = f2bf(o0);
        Abf[(i0 + wv + 4) * 64 + d] = f2bf(o1);
    }
}

// ---------------- Pass 1: sumexp per row (pad column included: +1, removed in pass2) ----
__global__ __launch_bounds__(256) void pass1_kernel(
    const unsigned short* __restrict__ Abf,
    const unsigned short* __restrict__ Bbf,
    const float* __restrict__ temp_p,
    float* __restrict__ sumexp)
{
    const int lane = threadIdx.x & 63;
    const int wv   = threadIdx.x >> 6;
    const int n    = lane & 15;
    const int quad = lane >> 4;
    const int r0   = blockIdx.x * 64 + wv * 16;
    const float T  = *temp_p;

    const short8 a0 = *(const short8*)(Abf + (size_t)(r0 + n) * 64 + quad * 8);
    const short8 a1 = *(const short8*)(Abf + (size_t)(r0 + n) * 64 + 32 + quad * 8);

    float rs[4] = {0.f, 0.f, 0.f, 0.f};
    const int ct0 = blockIdx.y * TPB;
    #pragma unroll 5
    for (int i = 0; i < TPB; ++i) {
        const unsigned short* bp = Bbf + (size_t)((ct0 + i) * 16 + n) * 64;
        const short8 b0 = *(const short8*)(bp + quad * 8);
        const short8 b1 = *(const short8*)(bp + 32 + quad * 8);
        f32x4 d = {0.f, 0.f, 0.f, 0.f};
        d = __builtin_amdgcn_mfma_f32_16x16x32_bf16(a0, b0, d, 0, 0, 0);
        d = __builtin_amdgcn_mfma_f32_16x16x32_bf16(a1, b1, d, 0, 0, 0);
        #pragma unroll
        for (int r = 0; r < 4; ++r) rs[r] += __expf(T * d[r]);
    }
    #pragma unroll
    for (int r = 0; r < 4; ++r) {
        float v = rs[r];
        v += __shfl_xor(v, 1, 64);
        v += __shfl_xor(v, 2, 64);
        v += __shfl_xor(v, 4, 64);
        v += __shfl_xor(v, 8, 64);
        if (n == 0) atomicAdd(&sumexp[r0 + quad * 4 + r], v);
    }
}

// ---------------- Pass 2: KL accumulation ----------------
__global__ __launch_bounds__(256) void pass2_kernel(
    const unsigned short* __restrict__ Abf,
    const unsigned short* __restrict__ Bbf,
    const float* __restrict__ adj,
    const float* __restrict__ temp_p,
    const float* __restrict__ sumexp,
    float* __restrict__ acc)
{
    const int lane = threadIdx.x & 63;
    const int wv   = threadIdx.x >> 6;
    const int n    = lane & 15;
    const int quad = lane >> 4;
    const int r0   = blockIdx.x * 64 + wv * 16;
    const float T  = *temp_p;

    const short8 a0 = *(const short8*)(Abf + (size_t)(r0 + n) * 64 + quad * 8);
    const short8 a1 = *(const short8*)(Abf + (size_t)(r0 + n) * 64 + 32 + quad * 8);

    float lse[4];
    const float* adjr[4];
    #pragma unroll
    for (int r = 0; r < 4; ++r) {
        int row = r0 + quad * 4 + r;
        lse[r]  = __logf(sumexp[row] - 1.0f);  // remove pad column's exp(0)=1
        adjr[r] = adj + (size_t)row * NM1;
    }

    float local = 0.f;
    const int ct0 = blockIdx.y * TPB;
    #pragma unroll 5
    for (int i = 0; i < TPB; ++i) {
        const int j = (ct0 + i) * 16 + n;
        const unsigned short* bp = Bbf + (size_t)j * 64;
        const short8 b0 = *(const short8*)(bp + quad * 8);
        const short8 b1 = *(const short8*)(bp + 32 + quad * 8);
        f32x4 d = {0.f, 0.f, 0.f, 0.f};
        d = __builtin_amdgcn_mfma_f32_16x16x32_bf16(a0, b0, d, 0, 0, 0);
        d = __builtin_amdgcn_mfma_f32_16x16x32_bf16(a1, b1, d, 0, 0, 0);
        if (j < NM1) {
            #pragma unroll
            for (int r = 0; r < 4; ++r) {
                float yt = fmaxf(adjr[r][j], KLEPS);
                float lp = fmaxf(T * d[r] - lse[r], LOGEPS);  // log(clip(pred))
                local += yt * (__logf(yt) - lp);
            }
        }
    }
    #pragma unroll
    for (int m = 1; m <= 32; m <<= 1) local += __shfl_xor(local, m, 64);
    __shared__ float wacc[4];
    if (lane == 0) wacc[wv] = local;
    __syncthreads();
    if (threadIdx.x == 0) atomicAdd(acc, wacc[0] + wacc[1] + wacc[2] + wacc[3]);
}

// ---------------- Finalize ----------------
__global__ void fin_kernel(const float* __restrict__ acc,
                           const float* __restrict__ temp_p,
                           float* __restrict__ out)
{
    const float T = *temp_p;
    out[0] = acc[0] * (1.0f / (BATCH * 0.69314718055994531f)) + T * T * 0.01f;
}

extern "C" void kernel_launch(void* const* d_in, const int* in_sizes, int n_in,
                              void* d_out, int out_size, void* d_ws, size_t ws_size,
                              hipStream_t stream) {
    const int*   single_card = (const int*)d_in[0];
    const float* adj         = (const float*)d_in[1];
    const float* ce          = (const float*)d_in[2];
    const float* W1          = (const float*)d_in[3];
    const float* b1          = (const float*)d_in[4];
    const float* W2          = (const float*)d_in[5];
    const float* b2          = (const float*)d_in[6];
    const float* temp        = (const float*)d_in[7];

    char* ws = (char*)d_ws;
    unsigned short* Abf = (unsigned short*)(ws + A_OFF);
    unsigned short* Bbf = (unsigned short*)(ws + B_OFF);
    float* sumexp       = (float*)(ws + SUM_OFF);
    float* acc          = (float*)(ws + ACC_OFF);

    prep_kernel<<<12628, 256, 0, stream>>>(single_card, ce, W1, b1, W2, b2,
                                           Abf, Bbf, sumexp, acc);
    pass1_kernel<<<dim3(16, GRIDY), 256, 0, stream>>>(Abf, Bbf, temp, sumexp);
    pass2_kernel<<<dim3(16, GRIDY), 256, 0, stream>>>(Abf, Bbf, adj, temp, sumexp, acc);
    fin_kernel<<<1, 1, 0, stream>>>(acc, temp, (float*)d_out);
}

// Round 3
// 375.658 us; speedup vs baseline: 1.1397x; 1.1397x over previous
//
#include <hip/hip_runtime.h>

#define NUM_CARDS 50000
#define NM1 49999
#define BATCH 1024
#define BPAD 50176            // 784 col-tiles of 64; rows NM1..BPAD-1 of B are zero
#define NPAD (BPAD - NM1)     // 177 pad cols, each adds exp(0)=1 to S1
#define TILES_PER_BLOCK 8
#define GRIDY 98              // 98 * 8 = 784 tiles
#define KLEPS 1e-7f

typedef __attribute__((ext_vector_type(8))) short short8;   // 8 bf16
typedef __attribute__((ext_vector_type(4))) float f32x4;
typedef float f32x4u __attribute__((ext_vector_type(4), aligned(4)));  // adj rows are only 4B-aligned

// ws layout:
//   A bf16 : [0, 131072)                 1024*64*2
//   B bf16 : [131072, 6553600)           50176*64*2, row j = l2norm(card j+1), pads zero
//   S1..S4 : [6553600, 6569984)          4 x 1024 f32 (contiguous)
#define A_OFF  0
#define B_OFF  131072
#define S_OFF  6553600

__device__ inline unsigned short f2bf(float x) {
    unsigned int u = __float_as_uint(x);
    return (unsigned short)((u + 0x7FFFu + ((u >> 16) & 1u)) >> 16);  // RNE
}

// ---- prep: blocks [0,12544) normalize B; blocks [12544,12672) run the MLP; 12544 zeroes S ----
__global__ __launch_bounds__(256) void prep_kernel(
    const int* __restrict__ idx, const float* __restrict__ ce,
    const float* __restrict__ W1, const float* __restrict__ b1,
    const float* __restrict__ W2, const float* __restrict__ b2,
    unsigned short* __restrict__ Abf, unsigned short* __restrict__ Bbf,
    float* __restrict__ S)
{
    const int bid  = blockIdx.x;
    const int t    = threadIdx.x;
    const int lane = t & 63;
    const int wv   = t >> 6;

    if (bid < BPAD / 4) {
        const int j = bid * 4 + wv;
        float v = (j < NM1) ? ce[(size_t)(j + 1) * 64 + lane] : 0.f;
        float ss = v * v;
        #pragma unroll
        for (int m = 1; m <= 32; m <<= 1) ss += __shfl_xor(ss, m, 64);
        float inv = rsqrtf(fmaxf(ss, 1e-12f));
        Bbf[(size_t)j * 64 + lane] = f2bf((j < NM1) ? v * inv : 0.f);
        return;
    }

    if (bid == BPAD / 4) {
        for (int k = t; k < 4096; k += 256) S[k] = 0.f;
    }

    __shared__ float emb_s[8][64];
    __shared__ float hs[8][256];
    __shared__ int idx_s[8];
    const int i0 = (bid - BPAD / 4) * 8;
    if (t < 8) idx_s[t] = idx[i0 + t];
    __syncthreads();
    for (int e = t; e < 8 * 64; e += 256) {
        int g = e >> 6, k = e & 63;
        emb_s[g][k] = ce[idx_s[g] * 64 + k];
    }
    __syncthreads();
    {   // hidden layer
        const int j = t;
        float a8[8];
        float bj = b1[j];
        #pragma unroll
        for (int g = 0; g < 8; ++g) a8[g] = bj;
        for (int k = 0; k < 64; ++k) {
            float w = W1[k * 256 + j];
            #pragma unroll
            for (int g = 0; g < 8; ++g) a8[g] = fmaf(emb_s[g][k], w, a8[g]);
        }
        #pragma unroll
        for (int g = 0; g < 8; ++g) hs[g][j] = fmaxf(a8[g], 0.f);
    }
    __syncthreads();
    {   // output layer + l2norm -> bf16
        const int d = lane;
        float o0 = b2[d], o1 = b2[d];
        for (int j = 0; j < 256; ++j) {
            float w2 = W2[j * 64 + d];
            o0 = fmaf(hs[wv][j],     w2, o0);
            o1 = fmaf(hs[wv + 4][j], w2, o1);
        }
        float s0 = o0 * o0, s1 = o1 * o1;
        #pragma unroll
        for (int m = 1; m <= 32; m <<= 1) {
            s0 += __shfl_xor(s0, m, 64);
            s1 += __shfl_xor(s1, m, 64);
        }
        o0 *= rsqrtf(fmaxf(s0, 1e-12f));
        o1 *= rsqrtf(fmaxf(s1, 1e-12f));
        Abf[(i0 + wv) * 64 + d]     = f2bf(o0);
        Abf[(i0 + wv + 4) * 64 + d] = f2bf(o1);
    }
}

// ---- single fused sweep: S1=Σexp(Ts), S2=Σ yt·s, S3=Σ yt·log yt, S4=Σ yt ----
__global__ __launch_bounds__(256) void fused_kernel(
    const unsigned short* __restrict__ Abf,
    const unsigned short* __restrict__ Bbf,
    const float* __restrict__ adj,
    const float* __restrict__ temp_p,
    float* __restrict__ S)
{
    __shared__ float yts[64 * 67];   // 64x64 yt tile, stride 67 (2-way banks only)
    float* S1 = S; float* S2 = S + 1024; float* S3 = S + 2048; float* S4 = S + 3072;

    const int t    = threadIdx.x;
    const int lane = t & 63;
    const int wv   = t >> 6;
    const int n    = lane & 15;
    const int quad = lane >> 4;
    const int r0   = blockIdx.x * 64;
    const float T  = *temp_p;

    const size_t arow = (size_t)(r0 + wv * 16 + n) * 64;
    const short8 a0 = *(const short8*)(Abf + arow + quad * 8);
    const short8 a1 = *(const short8*)(Abf + arow + 32 + quad * 8);

    const int cg = t & 15;    // phase-A col group
    const int rb = t >> 4;    // phase-A row base (= wv*4 + quad)

    float s3[4] = {0,0,0,0}, s4[4] = {0,0,0,0};
    float rs1[4] = {0,0,0,0}, rs2[4] = {0,0,0,0};

    const int tile0 = blockIdx.y * TILES_PER_BLOCK;
    for (int i = 0; i < TILES_PER_BLOCK; ++i) {
        const int colbase = (tile0 + i) * 64;
        __syncthreads();   // previous tile's LDS reads complete
        // phase A: coalesced adj float4 loads -> yt -> LDS; S3,S4 inline
        const int c0 = colbase + cg * 4;
        #pragma unroll
        for (int p = 0; p < 4; ++p) {
            const int row = rb + p * 16;
            float y0 = 0.f, y1 = 0.f, y2 = 0.f, y3 = 0.f;
            const float* ap = adj + (size_t)(r0 + row) * NM1 + c0;
            if (c0 + 3 < NM1) {
                f32x4u v = *(const f32x4u*)ap;
                y0 = fmaxf(v.x, KLEPS); y1 = fmaxf(v.y, KLEPS);
                y2 = fmaxf(v.z, KLEPS); y3 = fmaxf(v.w, KLEPS);
                s3[p] += y0 * __logf(y0) + y1 * __logf(y1)
                       + y2 * __logf(y2) + y3 * __logf(y3);
                s4[p] += (y0 + y1) + (y2 + y3);
            } else {
                if (c0 + 0 < NM1) { y0 = fmaxf(ap[0], KLEPS); s3[p] += y0 * __logf(y0); s4[p] += y0; }
                if (c0 + 1 < NM1) { y1 = fmaxf(ap[1], KLEPS); s3[p] += y1 * __logf(y1); s4[p] += y1; }
                if (c0 + 2 < NM1) { y2 = fmaxf(ap[2], KLEPS); s3[p] += y2 * __logf(y2); s4[p] += y2; }
                if (c0 + 3 < NM1) { y3 = fmaxf(ap[3], KLEPS); s3[p] += y3 * __logf(y3); s4[p] += y3; }
            }
            float* lp = yts + row * 67 + cg * 4;
            lp[0] = y0; lp[1] = y1; lp[2] = y2; lp[3] = y3;
        }
        __syncthreads();
        // phase B: MFMA scores; S1 += exp(T s); S2 += yt*s from LDS
        #pragma unroll
        for (int c = 0; c < 4; ++c) {
            const int j = colbase + c * 16 + n;
            const unsigned short* bp = Bbf + (size_t)j * 64;
            const short8 b0 = *(const short8*)(bp + quad * 8);
            const short8 b1 = *(const short8*)(bp + 32 + quad * 8);
            f32x4 d = {0.f, 0.f, 0.f, 0.f};
            d = __builtin_amdgcn_mfma_f32_16x16x32_bf16(a0, b0, d, 0, 0, 0);
            d = __builtin_amdgcn_mfma_f32_16x16x32_bf16(a1, b1, d, 0, 0, 0);
            const float* yp = yts + (wv * 16 + quad * 4) * 67 + c * 16 + n;
            #pragma unroll
            for (int r = 0; r < 4; ++r) {
                rs1[r] += __expf(T * d[r]);
                rs2[r] += yp[r * 67] * d[r];
            }
        }
    }
    // reductions over the 16 n-lanes (bits 0-3 of lane in both mappings)
    #pragma unroll
    for (int r = 0; r < 4; ++r) {
        float v1 = rs1[r], v2 = rs2[r];
        v1 += __shfl_xor(v1, 1, 64); v2 += __shfl_xor(v2, 1, 64);
        v1 += __shfl_xor(v1, 2, 64); v2 += __shfl_xor(v2, 2, 64);
        v1 += __shfl_xor(v1, 4, 64); v2 += __shfl_xor(v2, 4, 64);
        v1 += __shfl_xor(v1, 8, 64); v2 += __shfl_xor(v2, 8, 64);
        if (n == 0) {
            const int row = r0 + wv * 16 + quad * 4 + r;
            atomicAdd(&S1[row], v1);
            atomicAdd(&S2[row], v2);
        }
    }
    #pragma unroll
    for (int p = 0; p < 4; ++p) {
        float v3 = s3[p], v4 = s4[p];
        v3 += __shfl_xor(v3, 1, 64); v4 += __shfl_xor(v4, 1, 64);
        v3 += __shfl_xor(v3, 2, 64); v4 += __shfl_xor(v4, 2, 64);
        v3 += __shfl_xor(v3, 4, 64); v4 += __shfl_xor(v4, 4, 64);
        v3 += __shfl_xor(v3, 8, 64); v4 += __shfl_xor(v4, 8, 64);
        if (n == 0) {
            const int row = r0 + rb + 16 * p;   // rb = wv*4 + quad
            atomicAdd(&S3[row], v3);
            atomicAdd(&S4[row], v4);
        }
    }
}

// ---- finalize: loss = Σ_r [S3 - T·S2 + log(S1-NPAD)·S4] / (B ln2) + T²/100 ----
__global__ __launch_bounds__(256) void fin_kernel(
    const float* __restrict__ S, const float* __restrict__ temp_p,
    float* __restrict__ out)
{
    const float* S1 = S; const float* S2 = S + 1024;
    const float* S3 = S + 2048; const float* S4 = S + 3072;
    const float T = *temp_p;
    const int t = threadIdx.x;
    float local = 0.f;
    #pragma unroll
    for (int p = 0; p < 4; ++p) {
        const int row = t + p * 256;
        float lse = __logf(S1[row] - (float)NPAD);
        local += S3[row] - T * S2[row] + lse * S4[row];
    }
    #pragma unroll
    for (int m = 1; m <= 32; m <<= 1) local += __shfl_xor(local, m, 64);
    __shared__ float wacc[4];
    if ((t & 63) == 0) wacc[t >> 6] = local;
    __syncthreads();
    if (t == 0)
        out[0] = (wacc[0] + wacc[1] + wacc[2] + wacc[3])
                 * (1.0f / (BATCH * 0.69314718055994531f))
               + T * T * 0.01f;
}

extern "C" void kernel_launch(void* const* d_in, const int* in_sizes, int n_in,
                              void* d_out, int out_size, void* d_ws, size_t ws_size,
                              hipStream_t stream) {
    const int*   single_card = (const int*)d_in[0];
    const float* adj         = (const float*)d_in[1];
    const float* ce          = (const float*)d_in[2];
    const float* W1          = (const float*)d_in[3];
    const float* b1          = (const float*)d_in[4];
    const float* W2          = (const float*)d_in[5];
    const float* b2          = (const float*)d_in[6];
    const float* temp        = (const float*)d_in[7];

    char* ws = (char*)d_ws;
    unsigned short* Abf = (unsigned short*)(ws + A_OFF);
    unsigned short* Bbf = (unsigned short*)(ws + B_OFF);
    float* S            = (float*)(ws + S_OFF);

    prep_kernel<<<BPAD / 4 + 128, 256, 0, stream>>>(single_card, ce, W1, b1, W2, b2,
                                                    Abf, Bbf, S);
    fused_kernel<<<dim3(16, GRIDY), 256, 0, stream>>>(Abf, Bbf, adj, temp, S);
    fin_kernel<<<1, 256, 0, stream>>>(S, temp, (float*)d_out);
}

// Round 4
// 360.133 us; speedup vs baseline: 1.1888x; 1.0431x over previous
//
#include <hip/hip_runtime.h>

#define NUM_CARDS 50000
#define NM1 49999
#define BATCH 1024
#define BPAD 50176            // padded cards: multiple of 512; B rows NM1..BPAD-1 are zero
#define NPAD (BPAD - NM1)     // 177 pad cols, each adds exp(0)=1 to S1
#define CARDS_PER_BLOCK 512   // 16 slabs of 32
#define GRIDY (BPAD / CARDS_PER_BLOCK)   // 98
#define KLEPS 1e-7f

typedef __attribute__((ext_vector_type(8))) short short8;   // 8 bf16
typedef __attribute__((ext_vector_type(4))) float f32x4;

// ws layout:
//   A bf16 : [0, 131072)        1024*64*2
//   B bf16 : [131072, 6553600)  50176*64*2, row j = l2norm(card j+1), pads zero
//   S1..S4 : [6553600, 6569984) 4 x 1024 f32
#define A_OFF  0
#define B_OFF  131072
#define S_OFF  6553600

__device__ inline unsigned short f2bf(float x) {
    unsigned int u = __float_as_uint(x);
    return (unsigned short)((u + 0x7FFFu + ((u >> 16) & 1u)) >> 16);  // RNE
}

// ---- prep: blocks [0,12544) normalize B; blocks [12544,12672) MLP; 12544 zeroes S ----
__global__ __launch_bounds__(256) void prep_kernel(
    const int* __restrict__ idx, const float* __restrict__ ce,
    const float* __restrict__ W1, const float* __restrict__ b1,
    const float* __restrict__ W2, const float* __restrict__ b2,
    unsigned short* __restrict__ Abf, unsigned short* __restrict__ Bbf,
    float* __restrict__ S)
{
    const int bid  = blockIdx.x;
    const int t    = threadIdx.x;
    const int lane = t & 63;
    const int wv   = t >> 6;

    if (bid < BPAD / 4) {
        const int j = bid * 4 + wv;
        float v = (j < NM1) ? ce[(size_t)(j + 1) * 64 + lane] : 0.f;
        float ss = v * v;
        #pragma unroll
        for (int m = 1; m <= 32; m <<= 1) ss += __shfl_xor(ss, m, 64);
        float inv = rsqrtf(fmaxf(ss, 1e-12f));
        Bbf[(size_t)j * 64 + lane] = f2bf((j < NM1) ? v * inv : 0.f);
        return;
    }

    if (bid == BPAD / 4) {
        for (int k = t; k < 4096; k += 256) S[k] = 0.f;
    }

    __shared__ float emb_s[8][64];
    __shared__ float hs[8][256];
    __shared__ int idx_s[8];
    const int i0 = (bid - BPAD / 4) * 8;
    if (t < 8) idx_s[t] = idx[i0 + t];
    __syncthreads();
    for (int e = t; e < 8 * 64; e += 256) {
        int g = e >> 6, k = e & 63;
        emb_s[g][k] = ce[idx_s[g] * 64 + k];
    }
    __syncthreads();
    {   // hidden layer
        const int j = t;
        float a8[8];
        float bj = b1[j];
        #pragma unroll
        for (int g = 0; g < 8; ++g) a8[g] = bj;
        for (int k = 0; k < 64; ++k) {
            float w = W1[k * 256 + j];
            #pragma unroll
            for (int g = 0; g < 8; ++g) a8[g] = fmaf(emb_s[g][k], w, a8[g]);
        }
        #pragma unroll
        for (int g = 0; g < 8; ++g) hs[g][j] = fmaxf(a8[g], 0.f);
    }
    __syncthreads();
    {   // output layer + l2norm -> bf16
        const int d = lane;
        float o0 = b2[d], o1 = b2[d];
        for (int j = 0; j < 256; ++j) {
            float w2 = W2[j * 64 + d];
            o0 = fmaf(hs[wv][j],     w2, o0);
            o1 = fmaf(hs[wv + 4][j], w2, o1);
        }
        float s0 = o0 * o0, s1 = o1 * o1;
        #pragma unroll
        for (int m = 1; m <= 32; m <<= 1) {
            s0 += __shfl_xor(s0, m, 64);
            s1 += __shfl_xor(s1, m, 64);
        }
        o0 *= rsqrtf(fmaxf(s0, 1e-12f));
        o1 *= rsqrtf(fmaxf(s1, 1e-12f));
        Abf[(i0 + wv) * 64 + d]     = f2bf(o0);
        Abf[(i0 + wv + 4) * 64 + d] = f2bf(o1);
    }
}

// ---- fused streaming sweep, no LDS, no barriers ----
// S1=Σexp(T·s), S2=Σ yt·s, S3=Σ yt·log yt, S4=Σ yt, all per batch row.
__global__ __launch_bounds__(256) void fused_kernel(
    const unsigned short* __restrict__ Abf,
    const unsigned short* __restrict__ Bbf,
    const float* __restrict__ adj,
    const float* __restrict__ temp_p,
    float* __restrict__ S)
{
    float* S1 = S; float* S2 = S + 1024; float* S3 = S + 2048; float* S4 = S + 3072;

    const int lane = threadIdx.x & 63;
    const int wv   = threadIdx.x >> 6;
    const int n    = lane & 15;
    const int quad = lane >> 4;
    const int r0   = blockIdx.x * 64 + wv * 16;   // this wave's 16-row group
    const float T  = *temp_p;

    // A fragments (held for the whole kernel)
    const size_t arow = (size_t)(r0 + n) * 64;
    const short8 a0 = *(const short8*)(Abf + arow + quad * 8);
    const short8 a1 = *(const short8*)(Abf + arow + 32 + quad * 8);

    // adj row pointers in C/D layout: this lane covers rows r0 + quad*4 + r
    const float* rowp[4];
    #pragma unroll
    for (int r = 0; r < 4; ++r) rowp[r] = adj + (size_t)(r0 + quad * 4 + r) * NM1;

    float rs1[4] = {0,0,0,0}, rs2[4] = {0,0,0,0};
    float rs3[4] = {0,0,0,0}, rs4[4] = {0,0,0,0};

    const int cbase0 = blockIdx.y * CARDS_PER_BLOCK;
    for (int slab = 0; slab < CARDS_PER_BLOCK / 32; ++slab) {
        const int cb = cbase0 + slab * 32;
        // ---- issue all loads for this slab ----
        const unsigned short* bp0 = Bbf + (size_t)(cb + n) * 64;        // card group 0
        const unsigned short* bp1 = Bbf + (size_t)(cb + 16 + n) * 64;   // card group 1
        const short8 b00 = *(const short8*)(bp0 + quad * 8);
        const short8 b01 = *(const short8*)(bp0 + 32 + quad * 8);
        const short8 b10 = *(const short8*)(bp1 + quad * 8);
        const short8 b11 = *(const short8*)(bp1 + 32 + quad * 8);
        const int j0 = cb + n;
        const int j1 = cb + 16 + n;
        const int jc0 = (j0 < NM1) ? j0 : 0;
        const int jc1 = (j1 < NM1) ? j1 : 0;
        float av0[4], av1[4];
        #pragma unroll
        for (int r = 0; r < 4; ++r) { av0[r] = rowp[r][jc0]; av1[r] = rowp[r][jc1]; }

        // ---- scores via MFMA ----
        f32x4 z = {0.f, 0.f, 0.f, 0.f};
        f32x4 d0 = __builtin_amdgcn_mfma_f32_16x16x32_bf16(
                       a1, b01, __builtin_amdgcn_mfma_f32_16x16x32_bf16(a0, b00, z, 0,0,0), 0,0,0);
        f32x4 d1 = __builtin_amdgcn_mfma_f32_16x16x32_bf16(
                       a1, b11, __builtin_amdgcn_mfma_f32_16x16x32_bf16(a0, b10, z, 0,0,0), 0,0,0);

        const bool v0 = (j0 < NM1), v1 = (j1 < NM1);
        #pragma unroll
        for (int r = 0; r < 4; ++r) {
            float t0 = fmaxf(av0[r], KLEPS);
            float y0 = v0 ? t0 : 0.f;
            float t1 = fmaxf(av1[r], KLEPS);
            float y1 = v1 ? t1 : 0.f;
            rs1[r] += __expf(T * d0[r]) + __expf(T * d1[r]);
            rs2[r] += y0 * d0[r] + y1 * d1[r];
            rs3[r] += y0 * __logf(t0) + y1 * __logf(t1);
            rs4[r] += y0 + y1;
        }
    }

    // reduce over the 16 n-lanes (lane bits 0-3), then one atomic per (row,sum)
    #pragma unroll
    for (int r = 0; r < 4; ++r) {
        float v1 = rs1[r], v2 = rs2[r], v3 = rs3[r], v4 = rs4[r];
        #pragma unroll
        for (int m = 1; m <= 8; m <<= 1) {
            v1 += __shfl_xor(v1, m, 64);
            v2 += __shfl_xor(v2, m, 64);
            v3 += __shfl_xor(v3, m, 64);
            v4 += __shfl_xor(v4, m, 64);
        }
        if (n == 0) {
            const int row = r0 + quad * 4 + r;
            atomicAdd(&S1[row], v1);
            atomicAdd(&S2[row], v2);
            atomicAdd(&S3[row], v3);
            atomicAdd(&S4[row], v4);
        }
    }
}

// ---- finalize: loss = Σ_r [S3 - T·S2 + log(S1-NPAD)·S4] / (B ln2) + T²/100 ----
__global__ __launch_bounds__(256) void fin_kernel(
    const float* __restrict__ S, const float* __restrict__ temp_p,
    float* __restrict__ out)
{
    const float* S1 = S; const float* S2 = S + 1024;
    const float* S3 = S + 2048; const float* S4 = S + 3072;
    const float T = *temp_p;
    const int t = threadIdx.x;
    float local = 0.f;
    #pragma unroll
    for (int p = 0; p < 4; ++p) {
        const int row = t + p * 256;
        float lse = __logf(S1[row] - (float)NPAD);
        local += S3[row] - T * S2[row] + lse * S4[row];
    }
    #pragma unroll
    for (int m = 1; m <= 32; m <<= 1) local += __shfl_xor(local, m, 64);
    __shared__ float wacc[4];
    if ((t & 63) == 0) wacc[t >> 6] = local;
    __syncthreads();
    if (t == 0)
        out[0] = (wacc[0] + wacc[1] + wacc[2] + wacc[3])
                 * (1.0f / (BATCH * 0.69314718055994531f))
               + T * T * 0.01f;
}

extern "C" void kernel_launch(void* const* d_in, const int* in_sizes, int n_in,
                              void* d_out, int out_size, void* d_ws, size_t ws_size,
                              hipStream_t stream) {
    const int*   single_card = (const int*)d_in[0];
    const float* adj         = (const float*)d_in[1];
    const float* ce          = (const float*)d_in[2];
    const float* W1          = (const float*)d_in[3];
    const float* b1          = (const float*)d_in[4];
    const float* W2          = (const float*)d_in[5];
    const float* b2          = (const float*)d_in[6];
    const float* temp        = (const float*)d_in[7];

    char* ws = (char*)d_ws;
    unsigned short* Abf = (unsigned short*)(ws + A_OFF);
    unsigned short* Bbf = (unsigned short*)(ws + B_OFF);
    float* S            = (float*)(ws + S_OFF);

    prep_kernel<<<BPAD / 4 + 128, 256, 0, stream>>>(single_card, ce, W1, b1, W2, b2,
                                                    Abf, Bbf, S);
    fused_kernel<<<dim3(16, GRIDY), 256, 0, stream>>>(Abf, Bbf, adj, temp, S);
    fin_kernel<<<1, 256, 0, stream>>>(S, temp, (float*)d_out);
}

// Round 5
// 355.001 us; speedup vs baseline: 1.2060x; 1.0145x over previous
//
#include <hip/hip_runtime.h>

#define NUM_CARDS 50000
#define NM1 49999
#define BATCH 1024
#define BPAD 50176            // padded cards: multiple of 512; B rows NM1..BPAD-1 are zero
#define NPAD (BPAD - NM1)     // 177 pad cards, each adds exp(0)=1 to S1
#define CARDS_PER_BLOCK 512   // 8 slabs of 64
#define GRIDY (BPAD / CARDS_PER_BLOCK)   // 98
#define KLEPS 1e-7f

typedef __attribute__((ext_vector_type(8))) short short8;   // 8 bf16
typedef __attribute__((ext_vector_type(4))) float f32x4;
typedef float f32x4u __attribute__((ext_vector_type(4), aligned(4)));  // adj rows only 4B-aligned

// ws layout:
//   A bf16 : [0, 131072)        1024*64*2
//   B bf16 : [131072, 6553600)  50176*64*2, row j = l2norm(card j+1), pads zero
//   S1..S4 : [6553600, 6569984) 4 x 1024 f32
#define A_OFF  0
#define B_OFF  131072
#define S_OFF  6553600

__device__ inline unsigned short f2bf(float x) {
    unsigned int u = __float_as_uint(x);
    return (unsigned short)((u + 0x7FFFu + ((u >> 16) & 1u)) >> 16);  // RNE
}

// ---- prep: blocks [0,12544) normalize B; blocks [12544,12672) MLP; 12544 zeroes S ----
__global__ __launch_bounds__(256) void prep_kernel(
    const int* __restrict__ idx, const float* __restrict__ ce,
    const float* __restrict__ W1, const float* __restrict__ b1,
    const float* __restrict__ W2, const float* __restrict__ b2,
    unsigned short* __restrict__ Abf, unsigned short* __restrict__ Bbf,
    float* __restrict__ S)
{
    const int bid  = blockIdx.x;
    const int t    = threadIdx.x;
    const int lane = t & 63;
    const int wv   = t >> 6;

    if (bid < BPAD / 4) {
        const int j = bid * 4 + wv;
        float v = (j < NM1) ? ce[(size_t)(j + 1) * 64 + lane] : 0.f;
        float ss = v * v;
        #pragma unroll
        for (int m = 1; m <= 32; m <<= 1) ss += __shfl_xor(ss, m, 64);
        float inv = rsqrtf(fmaxf(ss, 1e-12f));
        Bbf[(size_t)j * 64 + lane] = f2bf((j < NM1) ? v * inv : 0.f);
        return;
    }

    if (bid == BPAD / 4) {
        for (int k = t; k < 4096; k += 256) S[k] = 0.f;
    }

    __shared__ float emb_s[8][64];
    __shared__ float hs[8][256];
    __shared__ int idx_s[8];
    const int i0 = (bid - BPAD / 4) * 8;
    if (t < 8) idx_s[t] = idx[i0 + t];
    __syncthreads();
    for (int e = t; e < 8 * 64; e += 256) {
        int g = e >> 6, k = e & 63;
        emb_s[g][k] = ce[idx_s[g] * 64 + k];
    }
    __syncthreads();
    {   // hidden layer
        const int j = t;
        float a8[8];
        float bj = b1[j];
        #pragma unroll
        for (int g = 0; g < 8; ++g) a8[g] = bj;
        for (int k = 0; k < 64; ++k) {
            float w = W1[k * 256 + j];
            #pragma unroll
            for (int g = 0; g < 8; ++g) a8[g] = fmaf(emb_s[g][k], w, a8[g]);
        }
        #pragma unroll
        for (int g = 0; g < 8; ++g) hs[g][j] = fmaxf(a8[g], 0.f);
    }
    __syncthreads();
    {   // output layer + l2norm -> bf16
        const int d = lane;
        float o0 = b2[d], o1 = b2[d];
        for (int j = 0; j < 256; ++j) {
            float w2 = W2[j * 64 + d];
            o0 = fmaf(hs[wv][j],     w2, o0);
            o1 = fmaf(hs[wv + 4][j], w2, o1);
        }
        float s0 = o0 * o0, s1 = o1 * o1;
        #pragma unroll
        for (int m = 1; m <= 32; m <<= 1) {
            s0 += __shfl_xor(s0, m, 64);
            s1 += __shfl_xor(s1, m, 64);
        }
        o0 *= rsqrtf(fmaxf(s0, 1e-12f));
        o1 *= rsqrtf(fmaxf(s1, 1e-12f));
        Abf[(i0 + wv) * 64 + d]     = f2bf(o0);
        Abf[(i0 + wv + 4) * 64 + d] = f2bf(o1);
    }
}

// ---- fused streaming sweep: float4 adj loads, wave-private LDS score bounce, no barriers ----
// Per wave: 16 batch rows x 512 cards (8 slabs of 64).
// S1=sum exp(T*s) [score layout], S2=sum yt*s [via LDS realign], S3=sum yt*log yt, S4=sum yt.
__global__ __launch_bounds__(256, 4) void fused_kernel(
    const unsigned short* __restrict__ Abf,
    const unsigned short* __restrict__ Bbf,
    const float* __restrict__ adj,
    const float* __restrict__ temp_p,
    float* __restrict__ S)
{
    // 4 waves x 64 cards x 17 dwords (68B card stride kills bank conflicts)
    __shared__ float sc[4][64 * 17];
    float* S1 = S; float* S2 = S + 1024; float* S3 = S + 2048; float* S4 = S + 3072;

    const int lane = threadIdx.x & 63;
    const int wv   = threadIdx.x >> 6;
    const int m    = lane & 15;
    const int quad = lane >> 4;
    const int r0   = blockIdx.x * 64 + wv * 16;   // this wave's 16-row group
    const float T  = *temp_p;

    // A fragments (row = r0+m, dims quad*8..+7 and 32+quad*8..+7)
    const size_t arow = (size_t)(r0 + m) * 64;
    const short8 a0 = *(const short8*)(Abf + arow + quad * 8);
    const short8 a1 = *(const short8*)(Abf + arow + 32 + quad * 8);

    // adj row pointers for rows r0 + quad*4 + r (both the scores' rows and our loads' rows)
    const float* rowp[4];
    #pragma unroll
    for (int r = 0; r < 4; ++r) rowp[r] = adj + (size_t)(r0 + quad * 4 + r) * NM1;

    float rs1[4] = {0,0,0,0}, rs2[4] = {0,0,0,0};
    float rs3[4] = {0,0,0,0}, rs4[4] = {0,0,0,0};

    float* wbase = sc[wv];
    const int cbase0 = blockIdx.y * CARDS_PER_BLOCK;

    for (int slab = 0; slab < CARDS_PER_BLOCK / 64; ++slab) {
        const int cb = cbase0 + slab * 64;

        // ---- B fragments for 4 card groups (cards cb+16g+m) ----
        short8 b0[4], b1[4];
        #pragma unroll
        for (int g = 0; g < 4; ++g) {
            const unsigned short* bp = Bbf + (size_t)(cb + 16 * g + m) * 64;
            b0[g] = *(const short8*)(bp + quad * 8);
            b1[g] = *(const short8*)(bp + 32 + quad * 8);
        }

        // ---- adj float4 loads: row quad*4+r, cards cb+4m..+3 (coalesced 256B/quad-row) ----
        f32x4 y[4];   // y[r][k] = clipped yt, zeroed for invalid cards
        if (cb + 63 < NM1) {
            #pragma unroll
            for (int r = 0; r < 4; ++r) {
                f32x4u v = *(const f32x4u*)(rowp[r] + cb + 4 * m);
                f32x4 tv;
                tv.x = fmaxf(v.x, KLEPS); tv.y = fmaxf(v.y, KLEPS);
                tv.z = fmaxf(v.z, KLEPS); tv.w = fmaxf(v.w, KLEPS);
                rs3[r] += tv.x * __logf(tv.x) + tv.y * __logf(tv.y)
                        + tv.z * __logf(tv.z) + tv.w * __logf(tv.w);
                rs4[r] += (tv.x + tv.y) + (tv.z + tv.w);
                y[r] = tv;
            }
        } else {
            #pragma unroll
            for (int r = 0; r < 4; ++r) {
                #pragma unroll
                for (int k = 0; k < 4; ++k) {
                    const int c = cb + 4 * m + k;
                    float yv = 0.f;
                    if (c < NM1) {
                        float tvv = fmaxf(rowp[r][c], KLEPS);
                        rs3[r] += tvv * __logf(tvv);
                        rs4[r] += tvv;
                        yv = tvv;
                    }
                    y[r][k] = yv;
                }
            }
        }

        // ---- scores via MFMA: d[g][r] = s(row r0+quad*4+r, card cb+16g+m) ----
        f32x4 d[4];
        #pragma unroll
        for (int g = 0; g < 4; ++g) {
            f32x4 z = {0.f, 0.f, 0.f, 0.f};
            d[g] = __builtin_amdgcn_mfma_f32_16x16x32_bf16(
                       a1, b1[g],
                       __builtin_amdgcn_mfma_f32_16x16x32_bf16(a0, b0[g], z, 0,0,0),
                       0,0,0);
        }

        // S1 directly in score layout
        #pragma unroll
        for (int g = 0; g < 4; ++g) {
            rs1[0] += __expf(T * d[g][0]);
            rs1[1] += __expf(T * d[g][1]);
            rs1[2] += __expf(T * d[g][2]);
            rs1[3] += __expf(T * d[g][3]);
        }

        // ---- wave-private LDS bounce: write [card][row-quad] f32x4, read per-card ----
        #pragma unroll
        for (int g = 0; g < 4; ++g)
            *(f32x4*)(wbase + (16 * g + m) * 17 + quad * 4) = d[g];
        // same-wave RAW: compiler inserts lgkmcnt wait; no __syncthreads needed
        #pragma unroll
        for (int k = 0; k < 4; ++k) {
            f32x4 R = *(const f32x4*)(wbase + (4 * m + k) * 17 + quad * 4);
            rs2[0] += y[0][k] * R.x;
            rs2[1] += y[1][k] * R.y;
            rs2[2] += y[2][k] * R.z;
            rs2[3] += y[3][k] * R.w;
        }
    }

    // reduce over the 16 m-lanes (lane bits 0-3), then one atomic per (row,sum)
    #pragma unroll
    for (int r = 0; r < 4; ++r) {
        float v1 = rs1[r], v2 = rs2[r], v3 = rs3[r], v4 = rs4[r];
        #pragma unroll
        for (int s = 1; s <= 8; s <<= 1) {
            v1 += __shfl_xor(v1, s, 64);
            v2 += __shfl_xor(v2, s, 64);
            v3 += __shfl_xor(v3, s, 64);
            v4 += __shfl_xor(v4, s, 64);
        }
        if (m == 0) {
            const int row = r0 + quad * 4 + r;
            atomicAdd(&S1[row], v1);
            atomicAdd(&S2[row], v2);
            atomicAdd(&S3[row], v3);
            atomicAdd(&S4[row], v4);
        }
    }
}

// ---- finalize: loss = sum_r [S3 - T*S2 + log(S1-NPAD)*S4] / (B ln2) + T^2/100 ----
__global__ __launch_bounds__(256) void fin_kernel(
    const float* __restrict__ S, const float* __restrict__ temp_p,
    float* __restrict__ out)
{
    const float* S1 = S; const float* S2 = S + 1024;
    const float* S3 = S + 2048; const float* S4 = S + 3072;
    const float T = *temp_p;
    const int t = threadIdx.x;
    float local = 0.f;
    #pragma unroll
    for (int p = 0; p < 4; ++p) {
        const int row = t + p * 256;
        float lse = __logf(S1[row] - (float)NPAD);
        local += S3[row] - T * S2[row] + lse * S4[row];
    }
    #pragma unroll
    for (int s = 1; s <= 32; s <<= 1) local += __shfl_xor(local, s, 64);
    __shared__ float wacc[4];
    if ((t & 63) == 0) wacc[t >> 6] = local;
    __syncthreads();
    if (t == 0)
        out[0] = (wacc[0] + wacc[1] + wacc[2] + wacc[3])
                 * (1.0f / (BATCH * 0.69314718055994531f))
               + T * T * 0.01f;
}

extern "C" void kernel_launch(void* const* d_in, const int* in_sizes, int n_in,
                              void* d_out, int out_size, void* d_ws, size_t ws_size,
                              hipStream_t stream) {
    const int*   single_card = (const int*)d_in[0];
    const float* adj         = (const float*)d_in[1];
    const float* ce          = (const float*)d_in[2];
    const float* W1          = (const float*)d_in[3];
    const float* b1          = (const float*)d_in[4];
    const float* W2          = (const float*)d_in[5];
    const float* b2          = (const float*)d_in[6];
    const float* temp        = (const float*)d_in[7];

    char* ws = (char*)d_ws;
    unsigned short* Abf = (unsigned short*)(ws + A_OFF);
    unsigned short* Bbf = (unsigned short*)(ws + B_OFF);
    float* S            = (float*)(ws + S_OFF);

    prep_kernel<<<BPAD / 4 + 128, 256, 0, stream>>>(single_card, ce, W1, b1, W2, b2,
                                                    Abf, Bbf, S);
    fused_kernel<<<dim3(16, GRIDY), 256, 0, stream>>>(Abf, Bbf, adj, temp, S);
    fin_kernel<<<1, 256, 0, stream>>>(S, temp, (float*)d_out);
}